// Round 6
// baseline (167.140 us; speedup 1.0000x reference)
//
#include <hip/hip_runtime.h>
#include <cmath>

#pragma clang fp contract(off)

#define BB 32
#define QQ 2000
#define GG 64
#define CCH 80
#define TOPC 16

typedef unsigned long long u64;

// ---------------------------------------------------------------------------
// K1: cost matrix in [b][g][q] layout + per-query row argmin + zero-fill of
// the matching output region (serial_kernel scatters the ones later).
// Orientation: lane = gt index, each wave processes 16 queries serially.
// ---------------------------------------------------------------------------
__global__ __launch_bounds__(256) void cost_kernel(
    const float* __restrict__ logits, const float* __restrict__ boxes,
    const int* __restrict__ gtc, const float* __restrict__ gtb,
    const float* __restrict__ szout, const float* __restrict__ sztgt,
    float* __restrict__ cost, int* __restrict__ rowarg,
    float* __restrict__ out_match) {
#pragma clang fp contract(off)
  const int b = blockIdx.y;
  const int q0 = blockIdx.x * 64;
  const int t = threadIdx.x;
  const int w = t >> 6, lane = t & 63;

  __shared__ float4 s_qb[64];
  __shared__ float s_tile[64 * 65];

  const int gbase = (b * GG + lane) * 4;
  const float g0 = gtb[gbase + 0], g1 = gtb[gbase + 1];
  const float g2 = gtb[gbase + 2], g3 = gtb[gbase + 3];
  const float t0 = g0 / sztgt[gbase + 0], t1 = g1 / sztgt[gbase + 1];
  const float t2 = g2 / sztgt[gbase + 2], t3 = g3 / sztgt[gbase + 3];
  const float garea = (g2 - g0) * (g3 - g1);
  const float gcx = (g0 + g2) * 0.5f, gcy = (g1 + g3) * 0.5f;
  const float gw = g2 - g0, gh = g3 - g1;
  const float cxlo = gcx - 2.5f * gw, cxhi = gcx + 2.5f * gw;
  const float cylo = gcy - 2.5f * gh, cyhi = gcy + 2.5f * gh;
  const int cls = gtc[b * GG + lane];
  const float so0 = szout[b * 4 + 0], so1 = szout[b * 4 + 1];
  const float so2 = szout[b * 4 + 2], so3 = szout[b * 4 + 3];

  if (t < 64) {
    int q = q0 + t;
    s_qb[t] = (q < QQ) ? reinterpret_cast<const float4*>(boxes)[b * QQ + q]
                       : make_float4(0.f, 0.f, 1.f, 1.f);
  }
  __syncthreads();

  const float* lbase = logits + (size_t)b * QQ * CCH;
  for (int i = 0; i < 16; ++i) {
    const int qi = w * 16 + i;
    const int q = q0 + qi;
    float4 bx = s_qb[qi];
    float x1 = bx.x, y1 = bx.y, x2 = bx.z, y2 = bx.w;
    float on0 = x1 / so0, on1 = y1 / so1, on2 = x2 / so2, on3 = y2 / so3;
    float cx = (x1 + x2) * 0.5f, cy = (y1 + y2) * 0.5f;
    float areaa = (x2 - x1) * (y2 - y1);

    bool ib = (cx > g0) & (cx < g2) & (cy > g1) & (cy < g3);
    bool ic = (cx > cxlo) & (cx < cxhi) & (cy > cylo) & (cy < cyhi);
    bool fg = (__ballot(ib) != 0ull) || (__ballot(ic) != 0ull);
    float fgadd = fg ? 0.0f : 1e4f;

    float ltx = fmaxf(x1, g0), lty = fmaxf(y1, g1);
    float rbx = fminf(x2, g2), rby = fminf(y2, g3);
    float iw = fmaxf(rbx - ltx, 0.0f), ih = fmaxf(rby - lty, 0.0f);
    float inter = iw * ih;
    float uni = (areaa + garea) - inter;
    float iou = inter / uni;
    float ex1 = fminf(x1, g0), ey1 = fminf(y1, g1);
    float ex2 = fmaxf(x2, g2), ey2 = fmaxf(y2, g3);
    float ew = fmaxf(ex2 - ex1, 0.0f), eh = fmaxf(ey2 - ey1, 0.0f);
    float areac = ew * eh;
    float giou = iou - (areac - uni) / areac;

    float p = (q < QQ) ? lbase[(size_t)q * CCH + cls] : 0.5f;
    float negc = (0.75f * (p * p)) * (-logf((1.0f - p) + 1e-8f));
    float posc = (0.25f * ((1.0f - p) * (1.0f - p))) * (-logf(p + 1e-8f));
    float ccls = posc - negc;

    float cb = ((fabsf(on0 - t0) + fabsf(on1 - t1)) + fabsf(on2 - t2)) + fabsf(on3 - t3);
    float notbc = (ib & ic) ? 0.0f : 1.0f;
    float c = ((5.0f * cb + 2.0f * ccls) + 2.0f * (-giou)) + 100.0f * notbc;
    c = c + fgadd;

    s_tile[qi * 65 + lane] = c;

    float bv = c; int bg = lane;
    for (int off = 32; off; off >>= 1) {
      float ov = __shfl_down(bv, off, 64); int og = __shfl_down(bg, off, 64);
      if (ov < bv || (ov == bv && og < bg)) { bv = ov; bg = og; }
    }
    if (lane == 0 && q < QQ) rowarg[b * QQ + q] = bg;
  }
  __syncthreads();

  float* cb_out = cost + (size_t)b * GG * QQ;
  const int qi = t & 63;
  const int q = q0 + qi;
  if (q < QQ) {
    #pragma unroll
    for (int pass = 0; pass < 16; ++pass) {
      int g = (t >> 6) + pass * 4;
      cb_out[(size_t)g * QQ + q] = s_tile[qi * 65 + g];
    }
  }

  // zero-fill this block's slice of the matching output [b][q0..q0+63][:]
  int nq = QQ - q0; if (nq > 64) nq = 64;
  if (nq > 0) {
    float4* zb = reinterpret_cast<float4*>(out_match + ((size_t)b * QQ + q0) * GG);
    int n4 = nq * GG / 4;
    float4 z = make_float4(0.f, 0.f, 0.f, 0.f);
    for (int i = t; i < n4; i += 256) zb[i] = z;
  }
}

// ---------------------------------------------------------------------------
// K2a: ONE BLOCK (256 thr) per (b,col). Wave-independent selection with
// packed u64 keys ((order-encoded value)<<16 | idx), ONE barrier total:
//   - each wave extracts its own sorted top-5 iou / top-16 cost (no barriers)
//   - wave 0 merges the <=64 candidates to the exact global order.
// Key order == (value, index) lexicographic == stable argsort/top_k.
// ---------------------------------------------------------------------------
__global__ __launch_bounds__(256) void pick_kernel(
    const float* __restrict__ boxes, const float* __restrict__ gtb,
    const float* __restrict__ cost, short* __restrict__ lists,
    int* __restrict__ dynks) {
#pragma clang fp contract(off)
  const int bc = blockIdx.x;            // 0..BB*GG-1
  const int b = bc >> 6, col = bc & 63;
  const int tid = threadIdx.x;
  const int w = tid >> 6, lane = tid & 63;

  __shared__ u64 s_iou[4][5];
  __shared__ u64 s_cst[4][16];

  const int gbase = (b * GG + col) * 4;
  const float gx1 = gtb[gbase + 0], gy1 = gtb[gbase + 1];
  const float gx2 = gtb[gbase + 2], gy2 = gtb[gbase + 3];
  const float ga = (gx2 - gx1) * (gy2 - gy1);

  // ---- phase 1: iou keys, max-order; tie -> min q via (0xFFFF - q)
  u64 K[8];
  #pragma unroll
  for (int j = 0; j < 8; ++j) {
    int q = tid * 8 + j;                // per-thread contiguous
    float val = -1e30f;
    if (q < QQ) {
      float4 bx = reinterpret_cast<const float4*>(boxes)[b * QQ + q];
      float areaa = (bx.z - bx.x) * (bx.w - bx.y);
      float ltx = fmaxf(bx.x, gx1), lty = fmaxf(bx.y, gy1);
      float rbx = fminf(bx.z, gx2), rby = fminf(bx.w, gy2);
      float iw = fmaxf(rbx - ltx, 0.0f), ih = fmaxf(rby - lty, 0.0f);
      float inter = iw * ih;
      val = inter / ((areaa + ga) - inter);
    }
    unsigned u = __float_as_uint(val);
    u = (u & 0x80000000u) ? ~u : (u | 0x80000000u);
    K[j] = ((u64)u << 16) | (u64)(0xFFFF - q);
  }
  #pragma unroll
  for (int pass = 0; pass < 5; ++pass) {
    u64 bk = K[0];
    #pragma unroll
    for (int j = 1; j < 8; ++j) bk = (K[j] > bk) ? K[j] : bk;
    for (int off = 32; off; off >>= 1) {
      u64 ok = __shfl_down(bk, off, 64);
      bk = (ok > bk) ? ok : bk;
    }
    bk = __shfl(bk, 0, 64);
    if (lane == 0) s_iou[w][pass] = bk;
    int q = 0xFFFF - (int)(bk & 0xFFFFull);
    bool own = ((q >> 3) == tid);
    int jj = q & 7;
    #pragma unroll
    for (int j = 0; j < 8; ++j) if (own && jj == j) K[j] = 0ull;
  }

  // ---- phase 2: cost keys, min-order; tie -> min q
  const float* ccol = cost + (size_t)bc * QQ;
  {
    float cv[8];
    if (tid < 249) {                    // q = tid*8..tid*8+7 all < 2000
      const float4* c4 = reinterpret_cast<const float4*>(ccol) + tid * 2;
      float4 a = c4[0], d = c4[1];
      cv[0] = a.x; cv[1] = a.y; cv[2] = a.z; cv[3] = a.w;
      cv[4] = d.x; cv[5] = d.y; cv[6] = d.z; cv[7] = d.w;
    } else {
      #pragma unroll
      for (int j = 0; j < 8; ++j) {
        int q = tid * 8 + j;
        cv[j] = (q < QQ) ? ccol[q] : INFINITY;
      }
    }
    #pragma unroll
    for (int j = 0; j < 8; ++j) {
      unsigned u = __float_as_uint(cv[j]);
      u = (u & 0x80000000u) ? ~u : (u | 0x80000000u);
      K[j] = ((u64)u << 16) | (u64)(tid * 8 + j);
    }
  }
  #pragma unroll
  for (int pass = 0; pass < TOPC; ++pass) {
    u64 bk = K[0];
    #pragma unroll
    for (int j = 1; j < 8; ++j) bk = (K[j] < bk) ? K[j] : bk;
    for (int off = 32; off; off >>= 1) {
      u64 ok = __shfl_down(bk, off, 64);
      bk = (ok < bk) ? ok : bk;
    }
    bk = __shfl(bk, 0, 64);
    if (lane == 0) s_cst[w][pass] = bk;
    int q = (int)(bk & 0xFFFFull);
    bool own = ((q >> 3) == tid);
    int jj = q & 7;
    #pragma unroll
    for (int j = 0; j < 8; ++j) if (own && jj == j) K[j] = ~0ull;
  }

  __syncthreads();

  // ---- merge (wave 0 only): exact global order from per-wave sorted lists
  if (w == 0) {
    // iou: 20 candidates on lanes 0..19 (others key 0 = -inf in max-order)
    u64 k = (lane < 20) ? s_iou[lane / 5][lane % 5] : 0ull;
    float s = 0.0f;
    #pragma unroll
    for (int pass = 0; pass < 5; ++pass) {
      u64 bk = k;
      for (int off = 32; off; off >>= 1) {
        u64 ok = __shfl_down(bk, off, 64);
        bk = (ok > bk) ? ok : bk;
      }
      bk = __shfl(bk, 0, 64);
      unsigned u = (unsigned)(bk >> 16);
      u = (u & 0x80000000u) ? (u & 0x7FFFFFFFu) : ~u;
      s += __uint_as_float(u);          // descending, left-assoc (top_k sum)
      if (k == bk) k = 0ull;            // keys unique (q embedded)
    }
    int dynk = (int)s;                  // trunc == astype(int32)
    if (dynk < 1) dynk = 1;
    if (lane == 0) dynks[bc] = dynk;

    // cost: exactly 64 candidates, one per lane
    u64 c = s_cst[lane >> 4][lane & 15];
    #pragma unroll
    for (int pass = 0; pass < TOPC; ++pass) {
      u64 bk = c;
      for (int off = 32; off; off >>= 1) {
        u64 ok = __shfl_down(bk, off, 64);
        bk = (ok < bk) ? ok : bk;
      }
      bk = __shfl(bk, 0, 64);
      if (lane == 0) lists[bc * TOPC + pass] = (short)(bk & 0xFFFFull);
      if (c == bk) c = ~0ull;
    }
  }
}

// ---------------------------------------------------------------------------
// K2b: serial per-batch loop. Setup/teardown use 256 threads; the iterative
// loop runs entirely in wave 0 (wave-synchronous, ZERO barriers).
// ---------------------------------------------------------------------------
__global__ __launch_bounds__(256) void serial_kernel(
    const float* __restrict__ cost, const short* __restrict__ lists,
    const int* __restrict__ dynks, const int* __restrict__ rowarg,
    float* __restrict__ out_match, float* __restrict__ out_ids) {
#pragma clang fp contract(off)
  const int b = blockIdx.x;
  const int tid = threadIdx.x;

  __shared__ unsigned s_mlo[QQ], s_mhi[QQ];
  __shared__ int s_first[QQ];
  __shared__ int s_pushed[QQ];
  __shared__ short s_rarg[QQ];
  __shared__ short s_list[GG * TOPC];
  __shared__ int s_cnt[GG];
  __shared__ short s_chosen[GG];
  __shared__ unsigned long long s_pack[GG];
  __shared__ int s_added[GG];
  __shared__ short s_ucols[GG];
  __shared__ short s_fb[GG];
  __shared__ int s_nadd, s_nfb, s_Tv;

  for (int q = tid; q < QQ; q += 256) {
    s_mlo[q] = 0u; s_mhi[q] = 0u; s_first[q] = -1; s_pushed[q] = -1;
    s_rarg[q] = (short)rowarg[b * QQ + q];
  }
  for (int i = tid; i < GG * TOPC; i += 256) s_list[i] = lists[b * GG * TOPC + i];
  if (tid < GG) s_cnt[tid] = 0;
  __syncthreads();

  // initial matching: first dynk list entries per column
  if (tid < GG) {
    int dynk = dynks[b * GG + tid];
    s_cnt[tid] = dynk;
    for (int i = 0; i < dynk; ++i) {
      int q = s_list[tid * TOPC + i];
      if (tid < 32) atomicOr(&s_mlo[q], 1u << tid);
      else          atomicOr(&s_mhi[q], 1u << (tid - 32));
      s_first[q] = 0;                    // benign same-value race
    }
  }
  __syncthreads();

  // initial dedup: strip over-queries to one-hot at row argmin
  for (int q = tid; q < QQ; q += 256) {
    unsigned lo = s_mlo[q], hi = s_mhi[q];
    if (__popc(lo) + __popc(hi) > 1) {
      int bg = s_rarg[q];
      unsigned tl = lo, th = hi;
      while (tl) { int g = __ffs(tl) - 1; tl &= tl - 1; if (g != bg) atomicSub(&s_cnt[g], 1); }
      while (th) { int g = __ffs(th) + 31; th &= th - 1; if (g != bg) atomicSub(&s_cnt[g], 1); }
      bool had = (bg < 32) ? ((lo >> bg) & 1u) : ((hi >> (bg - 32)) & 1u);
      if (!had) atomicAdd(&s_cnt[bg], 1);
      s_mlo[q] = (bg < 32) ? (1u << bg) : 0u;
      s_mhi[q] = (bg >= 32) ? (1u << (bg - 32)) : 0u;
    }
  }
  __syncthreads();

  const float* costb = cost + (size_t)b * GG * QQ;

  // ======== single-wave loop: zero barriers ========
  if (tid < 64) {
    const int lane = tid;
    int T = 0;
    for (int iter = 0; iter < GG; ++iter) {
      unsigned long long bal = __ballot(s_cnt[lane] > 0);  // matched cols
      unsigned long long um = ~bal;                        // unmatched cols
      if (um == 0ull) break;
      T++;

      bool isun = (um >> lane) & 1ull;
      int nu = __popcll(um);
      int pos = __popcll(um & ((1ull << lane) - 1ull));
      if (isun) s_ucols[pos] = (short)lane;
      if (lane == 0) { s_nfb = 0; s_nadd = 0; }

      const int sg = lane >> 4, li = lane & 15;
      for (int base = 0; base < nu; base += 4) {
        int ci = base + sg;
        int col = (ci < nu) ? (int)s_ucols[ci] : -1;
        bool cand_un = false; int cq = 0;
        if (col >= 0) {
          cq = s_list[col * TOPC + li];
          cand_un = ((s_mlo[cq] | s_mhi[cq]) == 0u);
        }
        unsigned long long bb = __ballot(cand_un);
        unsigned sub = (unsigned)((bb >> (sg * 16)) & 0xFFFFull);
        if (col >= 0) {
          if (sub) {
            if (li == __ffs(sub) - 1) s_chosen[col] = (short)cq;
          } else if (li == 0) {
            int slot = atomicAdd(&s_nfb, 1);
            s_fb[slot] = (short)col;
          }
        }
      }

      int nfb = s_nfb;
      for (int fi = 0; fi < nfb; ++fi) {
        int col = s_fb[fi];
        const float* ccol = costb + (size_t)col * QQ;
        float bv = INFINITY; int bq = 0x7fffffff;
        for (int q2 = lane; q2 < QQ; q2 += 64) {
          if ((s_mlo[q2] | s_mhi[q2]) == 0u) {
            float cv = ccol[q2];
            if (cv < bv) { bv = cv; bq = q2; }
          }
        }
        for (int off = 32; off; off >>= 1) {
          float ov = __shfl_down(bv, off, 64); int oq = __shfl_down(bq, off, 64);
          if (ov < bv || (ov == bv && oq < bq)) { bv = ov; bq = oq; }
        }
        bq = __shfl(bq, 0, 64);
        if (bq == 0x7fffffff) {
          bv = INFINITY; bq = 0x7fffffff;
          for (int q2 = lane; q2 < QQ; q2 += 64) {
            float cv = ccol[q2];
            int k = (s_first[q2] >= 0) ? (iter + 1 - s_first[q2]) : 0;
            for (int tt = 0; tt < k; ++tt) cv += 1e5f;
            if (cv < bv) { bv = cv; bq = q2; }
          }
          for (int off = 32; off; off >>= 1) {
            float ov = __shfl_down(bv, off, 64); int oq = __shfl_down(bq, off, 64);
            if (ov < bv || (ov == bv && oq < bq)) { bv = ov; bq = oq; }
          }
          bq = __shfl(bq, 0, 64);
        }
        if (lane == 0) s_chosen[col] = (short)bq;
      }

      if (isun) {
        int q = s_chosen[lane];
        if (lane < 32) atomicOr(&s_mlo[q], 1u << lane);
        else           atomicOr(&s_mhi[q], 1u << (lane - 32));
        atomicAdd(&s_cnt[lane], 1);
        if (s_first[q] == -1) s_first[q] = iter + 1;   // same-value race ok
        if (atomicExch(&s_pushed[q], iter) != iter) {  // dedupe pushes
          int slot = atomicAdd(&s_nadd, 1);
          s_added[slot] = q;
        }
      }

      int na = s_nadd;
      if (lane < na) {
        int q = s_added[lane];
        unsigned lo = s_mlo[q], hi = s_mhi[q];
        if (__popc(lo) + __popc(hi) > 1) {
          int bg = s_rarg[q];
          unsigned tl = lo, th = hi;
          while (tl) { int g = __ffs(tl) - 1; tl &= tl - 1; if (g != bg) atomicSub(&s_cnt[g], 1); }
          while (th) { int g = __ffs(th) + 31; th &= th - 1; if (g != bg) atomicSub(&s_cnt[g], 1); }
          bool had = (bg < 32) ? ((lo >> bg) & 1u) : ((hi >> (bg - 32)) & 1u);
          if (!had) atomicAdd(&s_cnt[bg], 1);
          s_mlo[q] = (bg < 32) ? (1u << bg) : 0u;
          s_mhi[q] = (bg >= 32) ? (1u << (bg - 32)) : 0u;
        }
      }
    }
    if (tid == 0) s_Tv = T;
  }
  __syncthreads();
  const int T = s_Tv;

  // final ids: scatter-argmin over matched queries with exact penalty replay
  if (tid < GG) s_pack[tid] = 0xFFFFFFFFFFFFFFFFull;
  __syncthreads();
  for (int q = tid; q < QQ; q += 256) {
    unsigned lo = s_mlo[q], hi = s_mhi[q];
    if (lo | hi) {
      int g = lo ? (__ffs(lo) - 1) : (__ffs(hi) + 31);
      float cv = costb[(size_t)g * QQ + q];
      int k = T - s_first[q];
      for (int tt = 0; tt < k; ++tt) cv += 1e5f;
      unsigned ub = __float_as_uint(cv);
      ub = (ub & 0x80000000u) ? ~ub : (ub | 0x80000000u);
      unsigned long long pk = ((unsigned long long)ub << 16) | (unsigned)q;
      atomicMin(&s_pack[g], pk);
    }
  }
  __syncthreads();
  if (tid < GG) {
    unsigned long long pk = s_pack[tid];
    out_ids[b * GG + tid] =
        (pk == 0xFFFFFFFFFFFFFFFFull) ? 0.0f : (float)(pk & 0xFFFFull);
  }
  // scatter the ones into the pre-zeroed matching output
  for (int q = tid; q < QQ; q += 256) {
    unsigned lo = s_mlo[q], hi = s_mhi[q];
    if (lo | hi) {
      int g = lo ? (__ffs(lo) - 1) : (__ffs(hi) + 31);
      out_match[((size_t)b * QQ + q) * GG + g] = 1.0f;
    }
  }
}

extern "C" void kernel_launch(void* const* d_in, const int* in_sizes, int n_in,
                              void* d_out, int out_size, void* d_ws, size_t ws_size,
                              hipStream_t stream) {
  const float* logits = (const float*)d_in[0];
  const float* boxes  = (const float*)d_in[1];
  const int*   gtc    = (const int*)d_in[2];
  const float* gtbx   = (const float*)d_in[3];
  const float* szout  = (const float*)d_in[4];
  const float* sztgt  = (const float*)d_in[5];
  float* out = (float*)d_out;

  const size_t matchN  = (size_t)BB * QQ * GG;     // floats (output 0)
  const size_t rowargN = (size_t)BB * QQ;          // ints
  const size_t listsN  = (size_t)BB * GG * TOPC;   // shorts
  const size_t dynksN  = (size_t)BB * GG;          // ints

  char* p = (char*)d_ws;
  float* cost   = (float*)p;          p += matchN * 4;   // 16.4 MB (ws is ~268MB)
  int*   rowarg = (int*)p;            p += rowargN * 4;
  short* lists  = (short*)p;          p += listsN * 2;
  int*   dynks  = (int*)p;

  float* out_ids = out + matchN;

  hipLaunchKernelGGL(cost_kernel, dim3(32, BB), dim3(256), 0, stream,
                     logits, boxes, gtc, gtbx, szout, sztgt, cost, rowarg, out);
  hipLaunchKernelGGL(pick_kernel, dim3(BB * GG), dim3(256), 0, stream,
                     boxes, gtbx, cost, lists, dynks);
  hipLaunchKernelGGL(serial_kernel, dim3(BB), dim3(256), 0, stream,
                     cost, lists, dynks, rowarg, out, out_ids);
}

// Round 7
// 138.706 us; speedup vs baseline: 1.2050x; 1.2050x over previous
//
#include <hip/hip_runtime.h>
#include <cmath>

#pragma clang fp contract(off)

#define BB 32
#define QQ 2000
#define GG 64
#define CCH 80
#define TOPC 16

typedef unsigned long long u64;

// ---------------------------------------------------------------------------
// K1: cost matrix in [b][g][q] layout + per-query row argmin + zero-fill of
// the matching output region (serial_kernel scatters the ones later).
// ---------------------------------------------------------------------------
__global__ __launch_bounds__(256) void cost_kernel(
    const float* __restrict__ logits, const float* __restrict__ boxes,
    const int* __restrict__ gtc, const float* __restrict__ gtb,
    const float* __restrict__ szout, const float* __restrict__ sztgt,
    float* __restrict__ cost, int* __restrict__ rowarg,
    float* __restrict__ out_match) {
#pragma clang fp contract(off)
  const int b = blockIdx.y;
  const int q0 = blockIdx.x * 64;
  const int t = threadIdx.x;
  const int w = t >> 6, lane = t & 63;

  __shared__ float4 s_qb[64];
  __shared__ float s_tile[64 * 65];

  const int gbase = (b * GG + lane) * 4;
  const float g0 = gtb[gbase + 0], g1 = gtb[gbase + 1];
  const float g2 = gtb[gbase + 2], g3 = gtb[gbase + 3];
  const float t0 = g0 / sztgt[gbase + 0], t1 = g1 / sztgt[gbase + 1];
  const float t2 = g2 / sztgt[gbase + 2], t3 = g3 / sztgt[gbase + 3];
  const float garea = (g2 - g0) * (g3 - g1);
  const float gcx = (g0 + g2) * 0.5f, gcy = (g1 + g3) * 0.5f;
  const float gw = g2 - g0, gh = g3 - g1;
  const float cxlo = gcx - 2.5f * gw, cxhi = gcx + 2.5f * gw;
  const float cylo = gcy - 2.5f * gh, cyhi = gcy + 2.5f * gh;
  const int cls = gtc[b * GG + lane];
  const float so0 = szout[b * 4 + 0], so1 = szout[b * 4 + 1];
  const float so2 = szout[b * 4 + 2], so3 = szout[b * 4 + 3];

  if (t < 64) {
    int q = q0 + t;
    s_qb[t] = (q < QQ) ? reinterpret_cast<const float4*>(boxes)[b * QQ + q]
                       : make_float4(0.f, 0.f, 1.f, 1.f);
  }
  __syncthreads();

  const float* lbase = logits + (size_t)b * QQ * CCH;
  for (int i = 0; i < 16; ++i) {
    const int qi = w * 16 + i;
    const int q = q0 + qi;
    float4 bx = s_qb[qi];
    float x1 = bx.x, y1 = bx.y, x2 = bx.z, y2 = bx.w;
    float on0 = x1 / so0, on1 = y1 / so1, on2 = x2 / so2, on3 = y2 / so3;
    float cx = (x1 + x2) * 0.5f, cy = (y1 + y2) * 0.5f;
    float areaa = (x2 - x1) * (y2 - y1);

    bool ib = (cx > g0) & (cx < g2) & (cy > g1) & (cy < g3);
    bool ic = (cx > cxlo) & (cx < cxhi) & (cy > cylo) & (cy < cyhi);
    bool fg = (__ballot(ib) != 0ull) || (__ballot(ic) != 0ull);
    float fgadd = fg ? 0.0f : 1e4f;

    float ltx = fmaxf(x1, g0), lty = fmaxf(y1, g1);
    float rbx = fminf(x2, g2), rby = fminf(y2, g3);
    float iw = fmaxf(rbx - ltx, 0.0f), ih = fmaxf(rby - lty, 0.0f);
    float inter = iw * ih;
    float uni = (areaa + garea) - inter;
    float iou = inter / uni;
    float ex1 = fminf(x1, g0), ey1 = fminf(y1, g1);
    float ex2 = fmaxf(x2, g2), ey2 = fmaxf(y2, g3);
    float ew = fmaxf(ex2 - ex1, 0.0f), eh = fmaxf(ey2 - ey1, 0.0f);
    float areac = ew * eh;
    float giou = iou - (areac - uni) / areac;

    float p = (q < QQ) ? lbase[(size_t)q * CCH + cls] : 0.5f;
    float negc = (0.75f * (p * p)) * (-logf((1.0f - p) + 1e-8f));
    float posc = (0.25f * ((1.0f - p) * (1.0f - p))) * (-logf(p + 1e-8f));
    float ccls = posc - negc;

    float cb = ((fabsf(on0 - t0) + fabsf(on1 - t1)) + fabsf(on2 - t2)) + fabsf(on3 - t3);
    float notbc = (ib & ic) ? 0.0f : 1.0f;
    float c = ((5.0f * cb + 2.0f * ccls) + 2.0f * (-giou)) + 100.0f * notbc;
    c = c + fgadd;

    s_tile[qi * 65 + lane] = c;

    float bv = c; int bg = lane;
    for (int off = 32; off; off >>= 1) {
      float ov = __shfl_down(bv, off, 64); int og = __shfl_down(bg, off, 64);
      if (ov < bv || (ov == bv && og < bg)) { bv = ov; bg = og; }
    }
    if (lane == 0 && q < QQ) rowarg[b * QQ + q] = bg;
  }
  __syncthreads();

  float* cb_out = cost + (size_t)b * GG * QQ;
  const int qi = t & 63;
  const int q = q0 + qi;
  if (q < QQ) {
    #pragma unroll
    for (int pass = 0; pass < 16; ++pass) {
      int g = (t >> 6) + pass * 4;
      cb_out[(size_t)g * QQ + q] = s_tile[qi * 65 + g];
    }
  }

  int nq = QQ - q0; if (nq > 64) nq = 64;
  if (nq > 0) {
    float4* zb = reinterpret_cast<float4*>(out_match + ((size_t)b * QQ + q0) * GG);
    int n4 = nq * GG / 4;
    float4 z = make_float4(0.f, 0.f, 0.f, 0.f);
    for (int i = t; i < n4; i += 256) zb[i] = z;
  }
}

// ---------------------------------------------------------------------------
// block_select<TOPN>: exact sorted smallest-TOPN of the block's 2048 unique
// u64 keys (8/thread), via threshold-filter + rank. No long dependency
// chains: threshold t = TOPN-th smallest of 64 column-minima (columns of 32
// elements) is a PROVEN upper bound for the global TOPN-th (the TOPN columns
// with cmin<=t hold TOPN distinct keys <= t), and bounds survivors to
// TOPN*32 <= 512. Ranks are unique (keys unique) -> direct scatter to
// sorted order. Rare ns>64 path: exact wave-0 extraction fallback.
// ---------------------------------------------------------------------------
template <int TOPN>
__device__ __forceinline__ void block_select(
    u64 (&K)[8], int tid, u64* s_tmin, u64* s_cmin, u64* s_surv,
    u64* s_sorted, u64* s_thr, int* s_ns) {
  u64 m = K[0];
  #pragma unroll
  for (int j = 1; j < 8; ++j) m = (K[j] < m) ? K[j] : m;
  s_tmin[tid] = m;
  if (tid == 0) *s_ns = 0;
  __syncthreads();

  if (tid < 64) {
    u64 c = s_tmin[tid];
    u64 c1 = s_tmin[tid + 64], c2 = s_tmin[tid + 128], c3 = s_tmin[tid + 192];
    c = (c1 < c) ? c1 : c; c = (c2 < c) ? c2 : c; c = (c3 < c) ? c3 : c;
    s_cmin[tid] = c;
    int r = 0;
    for (int j = 0; j < 64; ++j) r += (s_cmin[j] < c) ? 1 : 0;
    if (r == TOPN - 1) *s_thr = c;       // unique rank -> exactly one writer
  }
  __syncthreads();

  const u64 t = *s_thr;
  int n = 0;
  #pragma unroll
  for (int j = 0; j < 8; ++j) n += (K[j] <= t) ? 1 : 0;
  if (n) {
    int base = atomicAdd(s_ns, n);
    int k = 0;
    #pragma unroll
    for (int j = 0; j < 8; ++j) if (K[j] <= t) s_surv[base + (k++)] = K[j];
  }
  __syncthreads();

  const int ns = *s_ns;                  // TOPN <= ns <= TOPN*32
  if (ns <= 64) {
    if (tid < ns && tid < 64) {
      u64 k = s_surv[tid];
      int r = 0;
      for (int j = 0; j < ns; ++j) r += (s_surv[j] < k) ? 1 : 0;
      if (r < TOPN) s_sorted[r] = k;
    }
  } else if (tid < 64) {
    // exact fallback: TOPN extraction passes over <=512 survivors (rare)
    for (int pass = 0; pass < TOPN; ++pass) {
      u64 bk = ~0ull;
      for (int idx = tid; idx < ns; idx += 64) {
        u64 v = s_surv[idx]; bk = (v < bk) ? v : bk;
      }
      for (int off = 32; off; off >>= 1) {
        u64 ok = __shfl_down(bk, off, 64); bk = (ok < bk) ? ok : bk;
      }
      bk = __shfl(bk, 0, 64);
      for (int idx = tid; idx < ns; idx += 64)
        if (s_surv[idx] == bk) s_surv[idx] = ~0ull;
      if (tid == 0) s_sorted[pass] = bk;
    }
  }
  __syncthreads();
}

// ---------------------------------------------------------------------------
// K2a: ONE BLOCK (256 thr) per (b,col). dynamic_k (top-5 iou, exact ordered
// sum) + top-16 smallest costs in exact stable order, both via block_select.
// Key encode: order-preserving u32 of float || 16-bit index; iou keys are
// bit-inverted so "max iou, min q" == "min key".
// ---------------------------------------------------------------------------
__global__ __launch_bounds__(256) void pick_kernel(
    const float* __restrict__ boxes, const float* __restrict__ gtb,
    const float* __restrict__ cost, short* __restrict__ lists,
    int* __restrict__ dynks) {
#pragma clang fp contract(off)
  const int bc = blockIdx.x;            // 0..BB*GG-1
  const int b = bc >> 6, col = bc & 63;
  const int tid = threadIdx.x;

  __shared__ u64 s_tmin[256];
  __shared__ u64 s_cmin[64];
  __shared__ u64 s_surv[512];
  __shared__ u64 s_sorted[TOPC];
  __shared__ u64 s_thr;
  __shared__ int s_ns;

  const int gbase = (b * GG + col) * 4;
  const float gx1 = gtb[gbase + 0], gy1 = gtb[gbase + 1];
  const float gx2 = gtb[gbase + 2], gy2 = gtb[gbase + 3];
  const float ga = (gx2 - gx1) * (gy2 - gy1);

  // ---- phase 1: iou top-5 (keys inverted: min-key == max-iou, min-q tie)
  u64 K[8];
  #pragma unroll
  for (int j = 0; j < 8; ++j) {
    int q = tid * 8 + j;
    float val = -1e30f;                  // pads lose every max comparison
    if (q < QQ) {
      float4 bx = reinterpret_cast<const float4*>(boxes)[b * QQ + q];
      float areaa = (bx.z - bx.x) * (bx.w - bx.y);
      float ltx = fmaxf(bx.x, gx1), lty = fmaxf(bx.y, gy1);
      float rbx = fminf(bx.z, gx2), rby = fminf(bx.w, gy2);
      float iw = fmaxf(rbx - ltx, 0.0f), ih = fmaxf(rby - lty, 0.0f);
      float inter = iw * ih;
      val = inter / ((areaa + ga) - inter);
    }
    unsigned u = __float_as_uint(val);
    u = (u & 0x80000000u) ? ~u : (u | 0x80000000u);
    K[j] = ~(((u64)u << 16) | (u64)(0xFFFF - q));
  }
  block_select<5>(K, tid, s_tmin, s_cmin, s_surv, s_sorted, &s_thr, &s_ns);
  if (tid == 0) {
    float s = 0.0f;
    for (int r = 0; r < 5; ++r) {        // descending iou, left-assoc sum
      u64 kk = ~s_sorted[r];
      unsigned u = (unsigned)(kk >> 16);
      u = (u & 0x80000000u) ? (u & 0x7FFFFFFFu) : ~u;
      s += __uint_as_float(u);
    }
    int dynk = (int)s;                   // trunc == astype(int32)
    if (dynk < 1) dynk = 1;
    dynks[bc] = dynk;
  }

  // ---- phase 2: top-16 smallest costs, stable (value, q) ascending
  const float* ccol = cost + (size_t)bc * QQ;
  {
    float cv[8];
    if (tid < 249) {
      const float4* c4 = reinterpret_cast<const float4*>(ccol) + tid * 2;
      float4 a = c4[0], d = c4[1];
      cv[0] = a.x; cv[1] = a.y; cv[2] = a.z; cv[3] = a.w;
      cv[4] = d.x; cv[5] = d.y; cv[6] = d.z; cv[7] = d.w;
    } else {
      #pragma unroll
      for (int j = 0; j < 8; ++j) {
        int q = tid * 8 + j;
        cv[j] = (q < QQ) ? ccol[q] : INFINITY;
      }
    }
    #pragma unroll
    for (int j = 0; j < 8; ++j) {
      unsigned u = __float_as_uint(cv[j]);
      u = (u & 0x80000000u) ? ~u : (u | 0x80000000u);
      K[j] = ((u64)u << 16) | (u64)(tid * 8 + j);
    }
  }
  block_select<TOPC>(K, tid, s_tmin, s_cmin, s_surv, s_sorted, &s_thr, &s_ns);
  if (tid < TOPC) lists[bc * TOPC + tid] = (short)(s_sorted[tid] & 0xFFFFull);
}

// ---------------------------------------------------------------------------
// K2b: serial per-batch loop. Setup/teardown use 256 threads; the iterative
// loop runs entirely in wave 0 (wave-synchronous, ZERO barriers).
// ---------------------------------------------------------------------------
__global__ __launch_bounds__(256) void serial_kernel(
    const float* __restrict__ cost, const short* __restrict__ lists,
    const int* __restrict__ dynks, const int* __restrict__ rowarg,
    float* __restrict__ out_match, float* __restrict__ out_ids) {
#pragma clang fp contract(off)
  const int b = blockIdx.x;
  const int tid = threadIdx.x;

  __shared__ unsigned s_mlo[QQ], s_mhi[QQ];
  __shared__ int s_first[QQ];
  __shared__ int s_pushed[QQ];
  __shared__ short s_rarg[QQ];
  __shared__ short s_list[GG * TOPC];
  __shared__ int s_cnt[GG];
  __shared__ short s_chosen[GG];
  __shared__ unsigned long long s_pack[GG];
  __shared__ int s_added[GG];
  __shared__ short s_ucols[GG];
  __shared__ short s_fb[GG];
  __shared__ int s_nadd, s_nfb, s_Tv;

  for (int q = tid; q < QQ; q += 256) {
    s_mlo[q] = 0u; s_mhi[q] = 0u; s_first[q] = -1; s_pushed[q] = -1;
    s_rarg[q] = (short)rowarg[b * QQ + q];
  }
  for (int i = tid; i < GG * TOPC; i += 256) s_list[i] = lists[b * GG * TOPC + i];
  if (tid < GG) s_cnt[tid] = 0;
  __syncthreads();

  if (tid < GG) {
    int dynk = dynks[b * GG + tid];
    s_cnt[tid] = dynk;
    for (int i = 0; i < dynk; ++i) {
      int q = s_list[tid * TOPC + i];
      if (tid < 32) atomicOr(&s_mlo[q], 1u << tid);
      else          atomicOr(&s_mhi[q], 1u << (tid - 32));
      s_first[q] = 0;
    }
  }
  __syncthreads();

  for (int q = tid; q < QQ; q += 256) {
    unsigned lo = s_mlo[q], hi = s_mhi[q];
    if (__popc(lo) + __popc(hi) > 1) {
      int bg = s_rarg[q];
      unsigned tl = lo, th = hi;
      while (tl) { int g = __ffs(tl) - 1; tl &= tl - 1; if (g != bg) atomicSub(&s_cnt[g], 1); }
      while (th) { int g = __ffs(th) + 31; th &= th - 1; if (g != bg) atomicSub(&s_cnt[g], 1); }
      bool had = (bg < 32) ? ((lo >> bg) & 1u) : ((hi >> (bg - 32)) & 1u);
      if (!had) atomicAdd(&s_cnt[bg], 1);
      s_mlo[q] = (bg < 32) ? (1u << bg) : 0u;
      s_mhi[q] = (bg >= 32) ? (1u << (bg - 32)) : 0u;
    }
  }
  __syncthreads();

  const float* costb = cost + (size_t)b * GG * QQ;

  if (tid < 64) {
    const int lane = tid;
    int T = 0;
    for (int iter = 0; iter < GG; ++iter) {
      unsigned long long bal = __ballot(s_cnt[lane] > 0);
      unsigned long long um = ~bal;
      if (um == 0ull) break;
      T++;

      bool isun = (um >> lane) & 1ull;
      int nu = __popcll(um);
      int pos = __popcll(um & ((1ull << lane) - 1ull));
      if (isun) s_ucols[pos] = (short)lane;
      if (lane == 0) { s_nfb = 0; s_nadd = 0; }

      const int sg = lane >> 4, li = lane & 15;
      for (int base = 0; base < nu; base += 4) {
        int ci = base + sg;
        int col = (ci < nu) ? (int)s_ucols[ci] : -1;
        bool cand_un = false; int cq = 0;
        if (col >= 0) {
          cq = s_list[col * TOPC + li];
          cand_un = ((s_mlo[cq] | s_mhi[cq]) == 0u);
        }
        unsigned long long bb = __ballot(cand_un);
        unsigned sub = (unsigned)((bb >> (sg * 16)) & 0xFFFFull);
        if (col >= 0) {
          if (sub) {
            if (li == __ffs(sub) - 1) s_chosen[col] = (short)cq;
          } else if (li == 0) {
            int slot = atomicAdd(&s_nfb, 1);
            s_fb[slot] = (short)col;
          }
        }
      }

      int nfb = s_nfb;
      for (int fi = 0; fi < nfb; ++fi) {
        int col = s_fb[fi];
        const float* ccol = costb + (size_t)col * QQ;
        float bv = INFINITY; int bq = 0x7fffffff;
        for (int q2 = lane; q2 < QQ; q2 += 64) {
          if ((s_mlo[q2] | s_mhi[q2]) == 0u) {
            float cv = ccol[q2];
            if (cv < bv) { bv = cv; bq = q2; }
          }
        }
        for (int off = 32; off; off >>= 1) {
          float ov = __shfl_down(bv, off, 64); int oq = __shfl_down(bq, off, 64);
          if (ov < bv || (ov == bv && oq < bq)) { bv = ov; bq = oq; }
        }
        bq = __shfl(bq, 0, 64);
        if (bq == 0x7fffffff) {
          bv = INFINITY; bq = 0x7fffffff;
          for (int q2 = lane; q2 < QQ; q2 += 64) {
            float cv = ccol[q2];
            int k = (s_first[q2] >= 0) ? (iter + 1 - s_first[q2]) : 0;
            for (int tt = 0; tt < k; ++tt) cv += 1e5f;
            if (cv < bv) { bv = cv; bq = q2; }
          }
          for (int off = 32; off; off >>= 1) {
            float ov = __shfl_down(bv, off, 64); int oq = __shfl_down(bq, off, 64);
            if (ov < bv || (ov == bv && oq < bq)) { bv = ov; bq = oq; }
          }
          bq = __shfl(bq, 0, 64);
        }
        if (lane == 0) s_chosen[col] = (short)bq;
      }

      if (isun) {
        int q = s_chosen[lane];
        if (lane < 32) atomicOr(&s_mlo[q], 1u << lane);
        else           atomicOr(&s_mhi[q], 1u << (lane - 32));
        atomicAdd(&s_cnt[lane], 1);
        if (s_first[q] == -1) s_first[q] = iter + 1;
        if (atomicExch(&s_pushed[q], iter) != iter) {
          int slot = atomicAdd(&s_nadd, 1);
          s_added[slot] = q;
        }
      }

      int na = s_nadd;
      if (lane < na) {
        int q = s_added[lane];
        unsigned lo = s_mlo[q], hi = s_mhi[q];
        if (__popc(lo) + __popc(hi) > 1) {
          int bg = s_rarg[q];
          unsigned tl = lo, th = hi;
          while (tl) { int g = __ffs(tl) - 1; tl &= tl - 1; if (g != bg) atomicSub(&s_cnt[g], 1); }
          while (th) { int g = __ffs(th) + 31; th &= th - 1; if (g != bg) atomicSub(&s_cnt[g], 1); }
          bool had = (bg < 32) ? ((lo >> bg) & 1u) : ((hi >> (bg - 32)) & 1u);
          if (!had) atomicAdd(&s_cnt[bg], 1);
          s_mlo[q] = (bg < 32) ? (1u << bg) : 0u;
          s_mhi[q] = (bg >= 32) ? (1u << (bg - 32)) : 0u;
        }
      }
    }
    if (tid == 0) s_Tv = T;
  }
  __syncthreads();
  const int T = s_Tv;

  if (tid < GG) s_pack[tid] = 0xFFFFFFFFFFFFFFFFull;
  __syncthreads();
  for (int q = tid; q < QQ; q += 256) {
    unsigned lo = s_mlo[q], hi = s_mhi[q];
    if (lo | hi) {
      int g = lo ? (__ffs(lo) - 1) : (__ffs(hi) + 31);
      float cv = costb[(size_t)g * QQ + q];
      int k = T - s_first[q];
      for (int tt = 0; tt < k; ++tt) cv += 1e5f;
      unsigned ub = __float_as_uint(cv);
      ub = (ub & 0x80000000u) ? ~ub : (ub | 0x80000000u);
      unsigned long long pk = ((unsigned long long)ub << 16) | (unsigned)q;
      atomicMin(&s_pack[g], pk);
    }
  }
  __syncthreads();
  if (tid < GG) {
    unsigned long long pk = s_pack[tid];
    out_ids[b * GG + tid] =
        (pk == 0xFFFFFFFFFFFFFFFFull) ? 0.0f : (float)(pk & 0xFFFFull);
  }
  for (int q = tid; q < QQ; q += 256) {
    unsigned lo = s_mlo[q], hi = s_mhi[q];
    if (lo | hi) {
      int g = lo ? (__ffs(lo) - 1) : (__ffs(hi) + 31);
      out_match[((size_t)b * QQ + q) * GG + g] = 1.0f;
    }
  }
}

extern "C" void kernel_launch(void* const* d_in, const int* in_sizes, int n_in,
                              void* d_out, int out_size, void* d_ws, size_t ws_size,
                              hipStream_t stream) {
  const float* logits = (const float*)d_in[0];
  const float* boxes  = (const float*)d_in[1];
  const int*   gtc    = (const int*)d_in[2];
  const float* gtbx   = (const float*)d_in[3];
  const float* szout  = (const float*)d_in[4];
  const float* sztgt  = (const float*)d_in[5];
  float* out = (float*)d_out;

  const size_t matchN  = (size_t)BB * QQ * GG;
  const size_t rowargN = (size_t)BB * QQ;
  const size_t listsN  = (size_t)BB * GG * TOPC;

  char* p = (char*)d_ws;
  float* cost   = (float*)p;          p += matchN * 4;
  int*   rowarg = (int*)p;            p += rowargN * 4;
  short* lists  = (short*)p;          p += listsN * 2;
  int*   dynks  = (int*)p;

  float* out_ids = out + matchN;

  hipLaunchKernelGGL(cost_kernel, dim3(32, BB), dim3(256), 0, stream,
                     logits, boxes, gtc, gtbx, szout, sztgt, cost, rowarg, out);
  hipLaunchKernelGGL(pick_kernel, dim3(BB * GG), dim3(256), 0, stream,
                     boxes, gtbx, cost, lists, dynks);
  hipLaunchKernelGGL(serial_kernel, dim3(BB), dim3(256), 0, stream,
                     cost, lists, dynks, rowarg, out, out_ids);
}

// Round 8
// 127.596 us; speedup vs baseline: 1.3099x; 1.0871x over previous
//
#include <hip/hip_runtime.h>
#include <cmath>

#pragma clang fp contract(off)

#define BB 32
#define QQ 2000
#define GG 64
#define CCH 80
#define TOPC 16
#define QT 32

typedef unsigned long long u64;

// ---------------------------------------------------------------------------
// K1: cost matrix in [b][g][q] layout + per-query row argmin + zero-fill of
// the matching output region. lane = gt; wave handles 8 queries. All focal
// gathers hoisted ahead of the barrier (one vmcnt drain, no per-i chain);
// row argmin moved to a post-barrier LDS scan; per-q box normalization
// precomputed once per tile (same ops, fewer redundant divides).
// ---------------------------------------------------------------------------
__global__ __launch_bounds__(256) void cost_kernel(
    const float* __restrict__ logits, const float* __restrict__ boxes,
    const int* __restrict__ gtc, const float* __restrict__ gtb,
    const float* __restrict__ szout, const float* __restrict__ sztgt,
    float* __restrict__ cost, int* __restrict__ rowarg,
    float* __restrict__ out_match) {
#pragma clang fp contract(off)
  const int b = blockIdx.y;
  const int q0 = blockIdx.x * QT;
  const int t = threadIdx.x;
  const int w = t >> 6, lane = t & 63;

  __shared__ float4 s_qb[QT];       // raw boxes
  __shared__ float4 s_qn[QT];       // boxes / size_out (per-q, hoisted divs)
  __shared__ float s_tile[QT * 65];

  // per-lane (= per-gt) constants
  const int gbase = (b * GG + lane) * 4;
  const float g0 = gtb[gbase + 0], g1 = gtb[gbase + 1];
  const float g2 = gtb[gbase + 2], g3 = gtb[gbase + 3];
  const float t0 = g0 / sztgt[gbase + 0], t1 = g1 / sztgt[gbase + 1];
  const float t2 = g2 / sztgt[gbase + 2], t3 = g3 / sztgt[gbase + 3];
  const float garea = (g2 - g0) * (g3 - g1);
  const float gcx = (g0 + g2) * 0.5f, gcy = (g1 + g3) * 0.5f;
  const float gw = g2 - g0, gh = g3 - g1;
  const float cxlo = gcx - 2.5f * gw, cxhi = gcx + 2.5f * gw;
  const float cylo = gcy - 2.5f * gh, cyhi = gcy + 2.5f * gh;
  const int cls = gtc[b * GG + lane];

  if (t < QT) {
    int q = q0 + t;
    float4 bx = (q < QQ) ? reinterpret_cast<const float4*>(boxes)[b * QQ + q]
                         : make_float4(0.f, 0.f, 1.f, 1.f);
    s_qb[t] = bx;
    float4 on;
    on.x = bx.x / szout[b * 4 + 0];
    on.y = bx.y / szout[b * 4 + 1];
    on.z = bx.z / szout[b * 4 + 2];
    on.w = bx.w / szout[b * 4 + 3];
    s_qn[t] = on;
  }

  // hoisted focal gathers: independent, all in flight before the barrier
  const float* lbase = logits + (size_t)b * QQ * CCH;
  float pv[8];
  #pragma unroll
  for (int i = 0; i < 8; ++i) {
    int q = q0 + w * 8 + i;
    pv[i] = (q < QQ) ? lbase[(size_t)q * CCH + cls] : 0.5f;
  }
  __syncthreads();

  #pragma unroll
  for (int i = 0; i < 8; ++i) {
    const int qi = w * 8 + i;             // wave-uniform query index
    float4 bx = s_qb[qi];
    float4 on = s_qn[qi];
    float x1 = bx.x, y1 = bx.y, x2 = bx.z, y2 = bx.w;
    float cx = (x1 + x2) * 0.5f, cy = (y1 + y2) * 0.5f;
    float areaa = (x2 - x1) * (y2 - y1);

    bool ib = (cx > g0) & (cx < g2) & (cy > g1) & (cy < g3);
    bool ic = (cx > cxlo) & (cx < cxhi) & (cy > cylo) & (cy < cyhi);
    bool fg = (__ballot(ib) != 0ull) || (__ballot(ic) != 0ull);
    float fgadd = fg ? 0.0f : 1e4f;

    float ltx = fmaxf(x1, g0), lty = fmaxf(y1, g1);
    float rbx = fminf(x2, g2), rby = fminf(y2, g3);
    float iw = fmaxf(rbx - ltx, 0.0f), ih = fmaxf(rby - lty, 0.0f);
    float inter = iw * ih;
    float uni = (areaa + garea) - inter;
    float iou = inter / uni;
    float ex1 = fminf(x1, g0), ey1 = fminf(y1, g1);
    float ex2 = fmaxf(x2, g2), ey2 = fmaxf(y2, g3);
    float ew = fmaxf(ex2 - ex1, 0.0f), eh = fmaxf(ey2 - ey1, 0.0f);
    float areac = ew * eh;
    float giou = iou - (areac - uni) / areac;

    float p = pv[i];
    float negc = (0.75f * (p * p)) * (-logf((1.0f - p) + 1e-8f));
    float posc = (0.25f * ((1.0f - p) * (1.0f - p))) * (-logf(p + 1e-8f));
    float ccls = posc - negc;

    float cb = ((fabsf(on.x - t0) + fabsf(on.y - t1)) + fabsf(on.z - t2)) + fabsf(on.w - t3);
    float notbc = (ib & ic) ? 0.0f : 1.0f;
    float c = ((5.0f * cb + 2.0f * ccls) + 2.0f * (-giou)) + 100.0f * notbc;
    c = c + fgadd;

    s_tile[qi * 65 + lane] = c;
  }
  __syncthreads();

  // row argmin via LDS scan (t<32), overlapped with the transposed stores.
  // strict < keeps first index == jnp.argmin tie semantics.
  if (t < QT) {
    int q = q0 + t;
    if (q < QQ) {
      const float* row = &s_tile[t * 65];
      float bv = row[0]; int bg = 0;
      #pragma unroll
      for (int g = 1; g < GG; ++g) {
        float cv = row[g];
        if (cv < bv) { bv = cv; bg = g; }
      }
      rowarg[b * QQ + q] = bg;
    }
  }

  // transposed store: lanes 0..31 -> consecutive q (coalesced 128B segments)
  float* cb_out = cost + (size_t)b * GG * QQ;
  const int qi = t & 31;
  const int q = q0 + qi;
  if (q < QQ) {
    #pragma unroll
    for (int pass = 0; pass < 8; ++pass) {
      int g = (t >> 5) + pass * 8;
      cb_out[(size_t)g * QQ + q] = s_tile[qi * 65 + g];
    }
  }

  // zero-fill this block's slice of the matching output
  int nq = QQ - q0; if (nq > QT) nq = QT;
  if (nq > 0) {
    float4* zb = reinterpret_cast<float4*>(out_match + ((size_t)b * QQ + q0) * GG);
    int n4 = nq * GG / 4;
    float4 z = make_float4(0.f, 0.f, 0.f, 0.f);
    for (int i = t; i < n4; i += 256) zb[i] = z;
  }
}

// ---------------------------------------------------------------------------
// block_select<TOPN>: exact sorted smallest-TOPN of the block's 2048 unique
// u64 keys (8/thread), via threshold-filter + rank. (unchanged from R7)
// ---------------------------------------------------------------------------
template <int TOPN>
__device__ __forceinline__ void block_select(
    u64 (&K)[8], int tid, u64* s_tmin, u64* s_cmin, u64* s_surv,
    u64* s_sorted, u64* s_thr, int* s_ns) {
  u64 m = K[0];
  #pragma unroll
  for (int j = 1; j < 8; ++j) m = (K[j] < m) ? K[j] : m;
  s_tmin[tid] = m;
  if (tid == 0) *s_ns = 0;
  __syncthreads();

  if (tid < 64) {
    u64 c = s_tmin[tid];
    u64 c1 = s_tmin[tid + 64], c2 = s_tmin[tid + 128], c3 = s_tmin[tid + 192];
    c = (c1 < c) ? c1 : c; c = (c2 < c) ? c2 : c; c = (c3 < c) ? c3 : c;
    s_cmin[tid] = c;
    int r = 0;
    for (int j = 0; j < 64; ++j) r += (s_cmin[j] < c) ? 1 : 0;
    if (r == TOPN - 1) *s_thr = c;       // unique rank -> exactly one writer
  }
  __syncthreads();

  const u64 t = *s_thr;
  int n = 0;
  #pragma unroll
  for (int j = 0; j < 8; ++j) n += (K[j] <= t) ? 1 : 0;
  if (n) {
    int base = atomicAdd(s_ns, n);
    int k = 0;
    #pragma unroll
    for (int j = 0; j < 8; ++j) if (K[j] <= t) s_surv[base + (k++)] = K[j];
  }
  __syncthreads();

  const int ns = *s_ns;                  // TOPN <= ns <= TOPN*32
  if (ns <= 64) {
    if (tid < ns && tid < 64) {
      u64 k = s_surv[tid];
      int r = 0;
      for (int j = 0; j < ns; ++j) r += (s_surv[j] < k) ? 1 : 0;
      if (r < TOPN) s_sorted[r] = k;
    }
  } else if (tid < 64) {
    for (int pass = 0; pass < TOPN; ++pass) {
      u64 bk = ~0ull;
      for (int idx = tid; idx < ns; idx += 64) {
        u64 v = s_surv[idx]; bk = (v < bk) ? v : bk;
      }
      for (int off = 32; off; off >>= 1) {
        u64 ok = __shfl_down(bk, off, 64); bk = (ok < bk) ? ok : bk;
      }
      bk = __shfl(bk, 0, 64);
      for (int idx = tid; idx < ns; idx += 64)
        if (s_surv[idx] == bk) s_surv[idx] = ~0ull;
      if (tid == 0) s_sorted[pass] = bk;
    }
  }
  __syncthreads();
}

// ---------------------------------------------------------------------------
// K2a: ONE BLOCK (256 thr) per (b,col). (unchanged from R7)
// ---------------------------------------------------------------------------
__global__ __launch_bounds__(256) void pick_kernel(
    const float* __restrict__ boxes, const float* __restrict__ gtb,
    const float* __restrict__ cost, short* __restrict__ lists,
    int* __restrict__ dynks) {
#pragma clang fp contract(off)
  const int bc = blockIdx.x;            // 0..BB*GG-1
  const int b = bc >> 6, col = bc & 63;
  const int tid = threadIdx.x;

  __shared__ u64 s_tmin[256];
  __shared__ u64 s_cmin[64];
  __shared__ u64 s_surv[512];
  __shared__ u64 s_sorted[TOPC];
  __shared__ u64 s_thr;
  __shared__ int s_ns;

  const int gbase = (b * GG + col) * 4;
  const float gx1 = gtb[gbase + 0], gy1 = gtb[gbase + 1];
  const float gx2 = gtb[gbase + 2], gy2 = gtb[gbase + 3];
  const float ga = (gx2 - gx1) * (gy2 - gy1);

  u64 K[8];
  #pragma unroll
  for (int j = 0; j < 8; ++j) {
    int q = tid * 8 + j;
    float val = -1e30f;
    if (q < QQ) {
      float4 bx = reinterpret_cast<const float4*>(boxes)[b * QQ + q];
      float areaa = (bx.z - bx.x) * (bx.w - bx.y);
      float ltx = fmaxf(bx.x, gx1), lty = fmaxf(bx.y, gy1);
      float rbx = fminf(bx.z, gx2), rby = fminf(bx.w, gy2);
      float iw = fmaxf(rbx - ltx, 0.0f), ih = fmaxf(rby - lty, 0.0f);
      float inter = iw * ih;
      val = inter / ((areaa + ga) - inter);
    }
    unsigned u = __float_as_uint(val);
    u = (u & 0x80000000u) ? ~u : (u | 0x80000000u);
    K[j] = ~(((u64)u << 16) | (u64)(0xFFFF - q));
  }
  block_select<5>(K, tid, s_tmin, s_cmin, s_surv, s_sorted, &s_thr, &s_ns);
  if (tid == 0) {
    float s = 0.0f;
    for (int r = 0; r < 5; ++r) {
      u64 kk = ~s_sorted[r];
      unsigned u = (unsigned)(kk >> 16);
      u = (u & 0x80000000u) ? (u & 0x7FFFFFFFu) : ~u;
      s += __uint_as_float(u);
    }
    int dynk = (int)s;
    if (dynk < 1) dynk = 1;
    dynks[bc] = dynk;
  }

  const float* ccol = cost + (size_t)bc * QQ;
  {
    float cv[8];
    if (tid < 249) {
      const float4* c4 = reinterpret_cast<const float4*>(ccol) + tid * 2;
      float4 a = c4[0], d = c4[1];
      cv[0] = a.x; cv[1] = a.y; cv[2] = a.z; cv[3] = a.w;
      cv[4] = d.x; cv[5] = d.y; cv[6] = d.z; cv[7] = d.w;
    } else {
      #pragma unroll
      for (int j = 0; j < 8; ++j) {
        int q = tid * 8 + j;
        cv[j] = (q < QQ) ? ccol[q] : INFINITY;
      }
    }
    #pragma unroll
    for (int j = 0; j < 8; ++j) {
      unsigned u = __float_as_uint(cv[j]);
      u = (u & 0x80000000u) ? ~u : (u | 0x80000000u);
      K[j] = ((u64)u << 16) | (u64)(tid * 8 + j);
    }
  }
  block_select<TOPC>(K, tid, s_tmin, s_cmin, s_surv, s_sorted, &s_thr, &s_ns);
  if (tid < TOPC) lists[bc * TOPC + tid] = (short)(s_sorted[tid] & 0xFFFFull);
}

// ---------------------------------------------------------------------------
// K2b: serial per-batch loop. (unchanged from R7)
// ---------------------------------------------------------------------------
__global__ __launch_bounds__(256) void serial_kernel(
    const float* __restrict__ cost, const short* __restrict__ lists,
    const int* __restrict__ dynks, const int* __restrict__ rowarg,
    float* __restrict__ out_match, float* __restrict__ out_ids) {
#pragma clang fp contract(off)
  const int b = blockIdx.x;
  const int tid = threadIdx.x;

  __shared__ unsigned s_mlo[QQ], s_mhi[QQ];
  __shared__ int s_first[QQ];
  __shared__ int s_pushed[QQ];
  __shared__ short s_rarg[QQ];
  __shared__ short s_list[GG * TOPC];
  __shared__ int s_cnt[GG];
  __shared__ short s_chosen[GG];
  __shared__ unsigned long long s_pack[GG];
  __shared__ int s_added[GG];
  __shared__ short s_ucols[GG];
  __shared__ short s_fb[GG];
  __shared__ int s_nadd, s_nfb, s_Tv;

  for (int q = tid; q < QQ; q += 256) {
    s_mlo[q] = 0u; s_mhi[q] = 0u; s_first[q] = -1; s_pushed[q] = -1;
    s_rarg[q] = (short)rowarg[b * QQ + q];
  }
  for (int i = tid; i < GG * TOPC; i += 256) s_list[i] = lists[b * GG * TOPC + i];
  if (tid < GG) s_cnt[tid] = 0;
  __syncthreads();

  if (tid < GG) {
    int dynk = dynks[b * GG + tid];
    s_cnt[tid] = dynk;
    for (int i = 0; i < dynk; ++i) {
      int q = s_list[tid * TOPC + i];
      if (tid < 32) atomicOr(&s_mlo[q], 1u << tid);
      else          atomicOr(&s_mhi[q], 1u << (tid - 32));
      s_first[q] = 0;
    }
  }
  __syncthreads();

  for (int q = tid; q < QQ; q += 256) {
    unsigned lo = s_mlo[q], hi = s_mhi[q];
    if (__popc(lo) + __popc(hi) > 1) {
      int bg = s_rarg[q];
      unsigned tl = lo, th = hi;
      while (tl) { int g = __ffs(tl) - 1; tl &= tl - 1; if (g != bg) atomicSub(&s_cnt[g], 1); }
      while (th) { int g = __ffs(th) + 31; th &= th - 1; if (g != bg) atomicSub(&s_cnt[g], 1); }
      bool had = (bg < 32) ? ((lo >> bg) & 1u) : ((hi >> (bg - 32)) & 1u);
      if (!had) atomicAdd(&s_cnt[bg], 1);
      s_mlo[q] = (bg < 32) ? (1u << bg) : 0u;
      s_mhi[q] = (bg >= 32) ? (1u << (bg - 32)) : 0u;
    }
  }
  __syncthreads();

  const float* costb = cost + (size_t)b * GG * QQ;

  if (tid < 64) {
    const int lane = tid;
    int T = 0;
    for (int iter = 0; iter < GG; ++iter) {
      unsigned long long bal = __ballot(s_cnt[lane] > 0);
      unsigned long long um = ~bal;
      if (um == 0ull) break;
      T++;

      bool isun = (um >> lane) & 1ull;
      int nu = __popcll(um);
      int pos = __popcll(um & ((1ull << lane) - 1ull));
      if (isun) s_ucols[pos] = (short)lane;
      if (lane == 0) { s_nfb = 0; s_nadd = 0; }

      const int sg = lane >> 4, li = lane & 15;
      for (int base = 0; base < nu; base += 4) {
        int ci = base + sg;
        int col = (ci < nu) ? (int)s_ucols[ci] : -1;
        bool cand_un = false; int cq = 0;
        if (col >= 0) {
          cq = s_list[col * TOPC + li];
          cand_un = ((s_mlo[cq] | s_mhi[cq]) == 0u);
        }
        unsigned long long bb = __ballot(cand_un);
        unsigned sub = (unsigned)((bb >> (sg * 16)) & 0xFFFFull);
        if (col >= 0) {
          if (sub) {
            if (li == __ffs(sub) - 1) s_chosen[col] = (short)cq;
          } else if (li == 0) {
            int slot = atomicAdd(&s_nfb, 1);
            s_fb[slot] = (short)col;
          }
        }
      }

      int nfb = s_nfb;
      for (int fi = 0; fi < nfb; ++fi) {
        int col = s_fb[fi];
        const float* ccol = costb + (size_t)col * QQ;
        float bv = INFINITY; int bq = 0x7fffffff;
        for (int q2 = lane; q2 < QQ; q2 += 64) {
          if ((s_mlo[q2] | s_mhi[q2]) == 0u) {
            float cv = ccol[q2];
            if (cv < bv) { bv = cv; bq = q2; }
          }
        }
        for (int off = 32; off; off >>= 1) {
          float ov = __shfl_down(bv, off, 64); int oq = __shfl_down(bq, off, 64);
          if (ov < bv || (ov == bv && oq < bq)) { bv = ov; bq = oq; }
        }
        bq = __shfl(bq, 0, 64);
        if (bq == 0x7fffffff) {
          bv = INFINITY; bq = 0x7fffffff;
          for (int q2 = lane; q2 < QQ; q2 += 64) {
            float cv = ccol[q2];
            int k = (s_first[q2] >= 0) ? (iter + 1 - s_first[q2]) : 0;
            for (int tt = 0; tt < k; ++tt) cv += 1e5f;
            if (cv < bv) { bv = cv; bq = q2; }
          }
          for (int off = 32; off; off >>= 1) {
            float ov = __shfl_down(bv, off, 64); int oq = __shfl_down(bq, off, 64);
            if (ov < bv || (ov == bv && oq < bq)) { bv = ov; bq = oq; }
          }
          bq = __shfl(bq, 0, 64);
        }
        if (lane == 0) s_chosen[col] = (short)bq;
      }

      if (isun) {
        int q = s_chosen[lane];
        if (lane < 32) atomicOr(&s_mlo[q], 1u << lane);
        else           atomicOr(&s_mhi[q], 1u << (lane - 32));
        atomicAdd(&s_cnt[lane], 1);
        if (s_first[q] == -1) s_first[q] = iter + 1;
        if (atomicExch(&s_pushed[q], iter) != iter) {
          int slot = atomicAdd(&s_nadd, 1);
          s_added[slot] = q;
        }
      }

      int na = s_nadd;
      if (lane < na) {
        int q = s_added[lane];
        unsigned lo = s_mlo[q], hi = s_mhi[q];
        if (__popc(lo) + __popc(hi) > 1) {
          int bg = s_rarg[q];
          unsigned tl = lo, th = hi;
          while (tl) { int g = __ffs(tl) - 1; tl &= tl - 1; if (g != bg) atomicSub(&s_cnt[g], 1); }
          while (th) { int g = __ffs(th) + 31; th &= th - 1; if (g != bg) atomicSub(&s_cnt[g], 1); }
          bool had = (bg < 32) ? ((lo >> bg) & 1u) : ((hi >> (bg - 32)) & 1u);
          if (!had) atomicAdd(&s_cnt[bg], 1);
          s_mlo[q] = (bg < 32) ? (1u << bg) : 0u;
          s_mhi[q] = (bg >= 32) ? (1u << (bg - 32)) : 0u;
        }
      }
    }
    if (tid == 0) s_Tv = T;
  }
  __syncthreads();
  const int T = s_Tv;

  if (tid < GG) s_pack[tid] = 0xFFFFFFFFFFFFFFFFull;
  __syncthreads();
  for (int q = tid; q < QQ; q += 256) {
    unsigned lo = s_mlo[q], hi = s_mhi[q];
    if (lo | hi) {
      int g = lo ? (__ffs(lo) - 1) : (__ffs(hi) + 31);
      float cv = costb[(size_t)g * QQ + q];
      int k = T - s_first[q];
      for (int tt = 0; tt < k; ++tt) cv += 1e5f;
      unsigned ub = __float_as_uint(cv);
      ub = (ub & 0x80000000u) ? ~ub : (ub | 0x80000000u);
      unsigned long long pk = ((unsigned long long)ub << 16) | (unsigned)q;
      atomicMin(&s_pack[g], pk);
    }
  }
  __syncthreads();
  if (tid < GG) {
    unsigned long long pk = s_pack[tid];
    out_ids[b * GG + tid] =
        (pk == 0xFFFFFFFFFFFFFFFFull) ? 0.0f : (float)(pk & 0xFFFFull);
  }
  for (int q = tid; q < QQ; q += 256) {
    unsigned lo = s_mlo[q], hi = s_mhi[q];
    if (lo | hi) {
      int g = lo ? (__ffs(lo) - 1) : (__ffs(hi) + 31);
      out_match[((size_t)b * QQ + q) * GG + g] = 1.0f;
    }
  }
}

extern "C" void kernel_launch(void* const* d_in, const int* in_sizes, int n_in,
                              void* d_out, int out_size, void* d_ws, size_t ws_size,
                              hipStream_t stream) {
  const float* logits = (const float*)d_in[0];
  const float* boxes  = (const float*)d_in[1];
  const int*   gtc    = (const int*)d_in[2];
  const float* gtbx   = (const float*)d_in[3];
  const float* szout  = (const float*)d_in[4];
  const float* sztgt  = (const float*)d_in[5];
  float* out = (float*)d_out;

  const size_t matchN  = (size_t)BB * QQ * GG;
  const size_t rowargN = (size_t)BB * QQ;
  const size_t listsN  = (size_t)BB * GG * TOPC;

  char* p = (char*)d_ws;
  float* cost   = (float*)p;          p += matchN * 4;
  int*   rowarg = (int*)p;            p += rowargN * 4;
  short* lists  = (short*)p;          p += listsN * 2;
  int*   dynks  = (int*)p;

  float* out_ids = out + matchN;

  hipLaunchKernelGGL(cost_kernel, dim3((QQ + QT - 1) / QT, BB), dim3(256), 0, stream,
                     logits, boxes, gtc, gtbx, szout, sztgt, cost, rowarg, out);
  hipLaunchKernelGGL(pick_kernel, dim3(BB * GG), dim3(256), 0, stream,
                     boxes, gtbx, cost, lists, dynks);
  hipLaunchKernelGGL(serial_kernel, dim3(BB), dim3(256), 0, stream,
                     cost, lists, dynks, rowarg, out, out_ids);
}